// Round 13
// baseline (918.641 us; speedup 1.0000x reference)
//
#include <hip/hip_runtime.h>

#define D 128
#define BN_EPS 1e-5f
#define MAXNB 16  // max scan blocks per type (n <= 65536)

typedef __attribute__((ext_vector_type(8))) short bf16x8;
typedef __attribute__((ext_vector_type(4))) float f32x4;

__device__ __forceinline__ unsigned short f2bf(float x) {
  unsigned u = __float_as_uint(x);
  u += 0x7FFF + ((u >> 16) & 1);  // round-to-nearest-even
  return (unsigned short)(u >> 16);
}

__device__ __forceinline__ void cvt8(float (&f)[8], bf16x8 r) {
  const unsigned* u = (const unsigned*)&r;
#pragma unroll
  for (int j = 0; j < 4; ++j) {
    f[2 * j] = __uint_as_float(u[j] << 16);
    f[2 * j + 1] = __uint_as_float(u[j] & 0xFFFF0000u);
  }
}

// ---------------------------------------------------------------------------
// edge-attr combo table: 9 combos + self-loop (4,0) at slot 9
__global__ __launch_bounds__(256) void k_etbl(const float* __restrict__ e1,
                                              const float* __restrict__ e2,
                                              float* __restrict__ etbl) {
  int idx = blockIdx.x * 256 + threadIdx.x;
  if (idx < 9 * D) {
    int combo = idx / D, c = idx % D;
    etbl[idx] = e1[(combo / 3) * D + c] + e2[(combo % 3) * D + c];
  } else if (idx < 10 * D) {
    int c = idx - 9 * D;
    etbl[idx] = e1[4 * D + c] + e2[c];
  }
}

// node embedding -> bf16 h
__global__ __launch_bounds__(256) void k_embed(const int* __restrict__ x,
                                               const float* __restrict__ emb1,
                                               const float* __restrict__ emb2,
                                               unsigned short* __restrict__ out,
                                               int n) {
  int idx = blockIdx.x * 256 + threadIdx.x;
  if (idx >= n * 32) return;
  int node = idx >> 5, c4 = idx & 31;
  int i1 = x[2 * node], i2 = x[2 * node + 1];
  float4 v1 = *(const float4*)(emb1 + (size_t)i1 * D + c4 * 4);
  float4 v2 = *(const float4*)(emb2 + (size_t)i2 * D + c4 * 4);
  ushort4 o;
  o.x = f2bf(v1.x + v2.x); o.y = f2bf(v1.y + v2.y);
  o.z = f2bf(v1.z + v2.z); o.w = f2bf(v1.w + v2.w);
  *(ushort4*)(out + (size_t)node * D + c4 * 4) = o;
}

// ---------------------------------------------------------------------------
// weight prep: Wt[n][k] = bf16(W[k][n] * scale)
__global__ __launch_bounds__(256) void k_wprep(const float* __restrict__ W,
                                               unsigned short* __restrict__ Wt,
                                               int K, int N, float scale) {
  int idx = blockIdx.x * 256 + threadIdx.x;
  if (idx >= K * N) return;
  int n = idx / K, k = idx - n * K;
  Wt[idx] = f2bf(W[(size_t)k * N + n] * scale);
}

__global__ __launch_bounds__(256) void k_bprep(
    const float* __restrict__ b110, const float* __restrict__ b030,
    const float* __restrict__ gb1, const float* __restrict__ gb2,
    const float* __restrict__ b021, float* __restrict__ bias0,
    float* __restrict__ biash, float* __restrict__ bias1) {
  int i = threadIdx.x;
  if (i < 128) {
    bias0[i] = 0.05f * (b110[i] + b030[i]);
    bias1[i] = 0.5f * gb2[i] + 0.05f * b021[i];
  }
  biash[i] = gb1[i];
}

// ---------------------------------------------------------------------------
// CSR build, dst-range partitioned (range r = blockIdx.x & 7 tracks the XCD
// round-robin so each cursor/payload region is written from ~one XCD)
#define ECHUNK 2048
struct EdgeArr {
  const int* ei[4];
  const int* ea[4];
  int* cur[4];
  int* pay[4];
};
struct CsrPtrs {
  int* cur[4];
  int* rp[4];
  int n[4];
};

__global__ __launch_bounds__(256) void k_hist_part(EdgeArr A, int E, int rsz) {
  int t = blockIdx.y;
  int r = blockIdx.x & 7;
  int chunk = blockIdx.x >> 3;
  const int* dstp = A.ei[t] + E;
  int* cur = A.cur[t];
  int lo = r * rsz, hi = lo + rsz;
  int base = chunk * ECHUNK;
  int end = min(base + ECHUNK, E);
  for (int e = base + (int)threadIdx.x; e < end; e += 256) {
    int dst = dstp[e];
    if (dst >= lo && dst < hi) atomicAdd(&cur[dst], 1);
  }
}

__global__ __launch_bounds__(256) void k_scan1(CsrPtrs p, int* __restrict__ bsum) {
  __shared__ int lds[256];
  int type = blockIdx.y;
  const int* cur = p.cur[type];
  int n = p.n[type];
  int base = blockIdx.x * 4096;
  int s = 0;
  for (int i = threadIdx.x; i < 4096; i += 256) {
    int idx = base + i;
    if (idx < n) s += cur[idx];
  }
  int tid = threadIdx.x;
  lds[tid] = s;
  __syncthreads();
  for (int off = 128; off > 0; off >>= 1) {
    if (tid < off) lds[tid] += lds[tid + off];
    __syncthreads();
  }
  if (tid == 0) bsum[type * MAXNB + blockIdx.x] = lds[0];
}

__global__ __launch_bounds__(64) void k_scan2(int* __restrict__ bsum) {
  int t = threadIdx.x;
  if (t < 4) {
    int run = 0;
    for (int i = 0; i < MAXNB; ++i) {
      int v = bsum[t * MAXNB + i];
      bsum[t * MAXNB + i] = run;
      run += v;
    }
  }
}

__global__ __launch_bounds__(256) void k_scan3(CsrPtrs p,
                                               const int* __restrict__ bsum,
                                               int E) {
  __shared__ int lds[256];
  int type = blockIdx.y;
  int* cur = p.cur[type];
  int* rp = p.rp[type];
  int n = p.n[type];
  int tid = threadIdx.x;
  if (blockIdx.x == 0 && tid == 0) rp[n] = E;
  int t0 = blockIdx.x * 4096 + tid * 16;
  int loc[16];
  int s = 0;
#pragma unroll
  for (int j = 0; j < 16; ++j) {
    int idx = t0 + j;
    int v = (idx < n) ? cur[idx] : 0;
    loc[j] = s;
    s += v;
  }
  lds[tid] = s;
  __syncthreads();
  for (int off = 1; off < 256; off <<= 1) {
    int v = (tid >= off) ? lds[tid - off] : 0;
    __syncthreads();
    lds[tid] += v;
    __syncthreads();
  }
  int off0 = bsum[type * MAXNB + blockIdx.x] + ((tid == 0) ? 0 : lds[tid - 1]);
#pragma unroll
  for (int j = 0; j < 16; ++j) {
    int idx = t0 + j;
    if (idx < n) {
      int v = off0 + loc[j];
      rp[idx] = v;
      cur[idx] = v;  // cursor becomes fill position
    }
  }
}

// payload = src | (combo << 16), dst-range partitioned
__global__ __launch_bounds__(256) void k_fill_part(EdgeArr A, int E, int rsz) {
  int t = blockIdx.y;
  int r = blockIdx.x & 7;
  int chunk = blockIdx.x >> 3;
  const int* ei = A.ei[t];
  const int* ea = A.ea[t];
  int* cur = A.cur[t];
  int* pay = A.pay[t];
  int lo = r * rsz, hi = lo + rsz;
  int base = chunk * ECHUNK;
  int end = min(base + ECHUNK, E);
  for (int e = base + (int)threadIdx.x; e < end; e += 256) {
    int dst = ei[E + e];
    if (dst >= lo && dst < hi) {
      int src = ei[e];
      int combo = ea[2 * e] * 3 + ea[2 * e + 1];
      int pos = atomicAdd(&cur[dst], 1);
      pay[pos] = src | (combo << 16);
    }
  }
}

// ---------------------------------------------------------------------------
// per-layer h normalization: hn = relu(h*sc + sh) in bf16
__global__ __launch_bounds__(256) void k_hnorm(const unsigned short* __restrict__ h,
                                               unsigned short* __restrict__ hn,
                                               const float* __restrict__ bnp,
                                               int n) {
  int idx = blockIdx.x * 256 + threadIdx.x;
  if (idx >= n * 16) return;
  int node = idx >> 4, sl = idx & 15, c = sl * 8;
  bf16x8 v = *(const bf16x8*)(h + (size_t)node * D + c);
  float f[8];
  cvt8(f, v);
  unsigned o[4];
#pragma unroll
  for (int j = 0; j < 4; ++j) {
    float a = fmaxf(fmaf(f[2 * j], bnp[c + 2 * j], bnp[D + c + 2 * j]), 0.f);
    float b = fmaxf(fmaf(f[2 * j + 1], bnp[c + 2 * j + 1], bnp[D + c + 2 * j + 1]), 0.f);
    o[j] = (unsigned)f2bf(a) | ((unsigned)f2bf(b) << 16);
  }
  *(uint4*)(hn + (size_t)node * D + c) = make_uint4(o[0], o[1], o[2], o[3]);
}

// ---------------------------------------------------------------------------
// Fused gather -> LDS tile -> B-stationary MFMA GEMM.
// Gathered sources have K=128; LDS tile is XOR-swizzled (chunk ^= row&7 in
// 16B units) so both the gather write and the GEMM ds_read_b128 hit the
// uniform bank-distribution floor.
// NOTE: gather sources (hs1/hs2) must NOT alias the output c within a layer —
// the launcher writes raw outputs to dedicated buffers (h0o/h1o).
constexpr int ETLD = 132;  // padded etbl row (floats) to spread bank groups

struct FArgs {
  const unsigned short* a1;  // dense A1 (when !G1)
  const unsigned short* hs1;
  const int* rp1;
  const int* pay1;
  int mode1;
  const unsigned short* wt1;
  const unsigned short* hs2;
  const int* rp2;
  const int* pay2;
  int mode2;
  const unsigned short* wt2;
  const float* etbl;
  const float* bias;
  void* c;
  float* stats;
  int M;
};

// gather one 64-row x 128-col tile into swizzled LDS (wave w -> rows w*16..+16)
__device__ __forceinline__ void gather_tile(
    unsigned short* At, const unsigned short* __restrict__ hsrc,
    const int* __restrict__ rp, const int* __restrict__ pay, int mode,
    const float* et, int row0, int M, int w, int grp, int sl, int c) {
  for (int i = 0; i < 16; ++i) {
    int r = w * 16 + i;
    int g = row0 + r;
    if (g >= M) break;
    float acc[8];
    if (grp == 0 && mode != 0) {
      bf16x8 hv = *(const bf16x8*)(hsrc + (size_t)g * D + c);
      float f[8];
      cvt8(f, hv);
      float m = (mode == 2) ? 2.1f : 1.0f;
      float4 ea = *(const float4*)(et + 9 * ETLD + c);
      float4 eb = *(const float4*)(et + 9 * ETLD + c + 4);
      acc[0] = m * f[0] + ea.x; acc[1] = m * f[1] + ea.y;
      acc[2] = m * f[2] + ea.z; acc[3] = m * f[3] + ea.w;
      acc[4] = m * f[4] + eb.x; acc[5] = m * f[5] + eb.y;
      acc[6] = m * f[6] + eb.z; acc[7] = m * f[7] + eb.w;
    } else {
#pragma unroll
      for (int j = 0; j < 8; ++j) acc[j] = 0.f;
    }
    int e1 = rp[g + 1];
    int e = rp[g] + grp;
    while (e + 4 < e1) {
      int p0 = pay[e], p1 = pay[e + 4];
      bf16x8 r0 = *(const bf16x8*)(hsrc + (size_t)(p0 & 0xFFFF) * D + c);
      bf16x8 r1 = *(const bf16x8*)(hsrc + (size_t)(p1 & 0xFFFF) * D + c);
      const float* t0 = et + (p0 >> 16) * ETLD + c;
      const float* t1 = et + (p1 >> 16) * ETLD + c;
      float f0[8], f1[8];
      cvt8(f0, r0);
      cvt8(f1, r1);
      float4 a0 = *(const float4*)t0, b0 = *(const float4*)(t0 + 4);
      float4 a1v = *(const float4*)t1, b1v = *(const float4*)(t1 + 4);
      acc[0] += (f0[0] + a0.x) + (f1[0] + a1v.x);
      acc[1] += (f0[1] + a0.y) + (f1[1] + a1v.y);
      acc[2] += (f0[2] + a0.z) + (f1[2] + a1v.z);
      acc[3] += (f0[3] + a0.w) + (f1[3] + a1v.w);
      acc[4] += (f0[4] + b0.x) + (f1[4] + b1v.x);
      acc[5] += (f0[5] + b0.y) + (f1[5] + b1v.y);
      acc[6] += (f0[6] + b0.z) + (f1[6] + b1v.z);
      acc[7] += (f0[7] + b0.w) + (f1[7] + b1v.w);
      e += 8;
    }
    if (e < e1) {
      int p0 = pay[e];
      bf16x8 r0 = *(const bf16x8*)(hsrc + (size_t)(p0 & 0xFFFF) * D + c);
      const float* t0 = et + (p0 >> 16) * ETLD + c;
      float f0[8];
      cvt8(f0, r0);
      float4 a0 = *(const float4*)t0, b0 = *(const float4*)(t0 + 4);
      acc[0] += f0[0] + a0.x; acc[1] += f0[1] + a0.y;
      acc[2] += f0[2] + a0.z; acc[3] += f0[3] + a0.w;
      acc[4] += f0[4] + b0.x; acc[5] += f0[5] + b0.y;
      acc[6] += f0[6] + b0.z; acc[7] += f0[7] + b0.w;
    }
#pragma unroll
    for (int j = 0; j < 8; ++j) {
      acc[j] += __shfl_xor(acc[j], 16);
      acc[j] += __shfl_xor(acc[j], 32);
    }
    if (grp == 0) {
      unsigned o0 = (unsigned)f2bf(acc[0]) | ((unsigned)f2bf(acc[1]) << 16);
      unsigned o1 = (unsigned)f2bf(acc[2]) | ((unsigned)f2bf(acc[3]) << 16);
      unsigned o2 = (unsigned)f2bf(acc[4]) | ((unsigned)f2bf(acc[5]) << 16);
      unsigned o3 = (unsigned)f2bf(acc[6]) | ((unsigned)f2bf(acc[7]) << 16);
      *(uint4*)(At + r * 128 + ((sl * 8) ^ ((r & 7) << 3))) =
          make_uint4(o0, o1, o2, o3);
    }
  }
}

template <int NCOLS, int K1, int K2, bool G1, bool G2, bool RELU, bool STATS,
          bool OBF16>
__global__ __launch_bounds__(256) void k_fused(FArgs F) {
  constexpr int WC = NCOLS / 4;
  constexpr int CF = WC / 16;
  constexpr int KF1 = K1 / 32;
  constexpr int KF2 = (K2 > 0) ? K2 / 32 : 1;
  static_assert(!G1 || K1 == 128, "gathered source must be K=128");
  static_assert(K2 == 0 || G2, "source 2 must be gathered when present");
  __shared__ float et[10 * ETLD];
  __shared__ unsigned short At1[G1 ? 64 * 128 : 8];
  __shared__ unsigned short At2[G2 ? 64 * 128 : 8];

  int tid = threadIdx.x;
  int w = tid >> 6, l = tid & 63;
  int grp = l >> 4, sl = l & 15, c = sl * 8;
  int lr = l & 15, lk = l >> 4;
  int row0 = blockIdx.x * 64;
  int M = F.M;

  for (int i = tid; i < 10 * D; i += 256)
    et[(i >> 7) * ETLD + (i & 127)] = F.etbl[i];
  __syncthreads();

  if (G1) gather_tile(At1, F.hs1, F.rp1, F.pay1, F.mode1, et, row0, M, w, grp, sl, c);
  if (G2) gather_tile(At2, F.hs2, F.rp2, F.pay2, F.mode2, et, row0, M, w, grp, sl, c);
  __syncthreads();

  int colbase = w * WC;
  f32x4 acc[4][CF];
#pragma unroll
  for (int rf = 0; rf < 4; ++rf)
#pragma unroll
    for (int cf = 0; cf < CF; ++cf) acc[rf][cf] = (f32x4)(0.f);

  // ---- source 1 ----
  {
    const unsigned short* ap[4];
    if (!G1) {
#pragma unroll
      for (int rf = 0; rf < 4; ++rf) {
        int r = row0 + rf * 16 + lr;
        if (r > M - 1) r = M - 1;
        ap[rf] = F.a1 + (size_t)r * K1 + lk * 8;
      }
    }
    bf16x8 B[CF][KF1];
#pragma unroll
    for (int cf = 0; cf < CF; ++cf)
#pragma unroll
      for (int kf = 0; kf < KF1; ++kf)
        B[cf][kf] = *(const bf16x8*)(F.wt1 + (size_t)(colbase + cf * 16 + lr) * K1 +
                                     kf * 32 + lk * 8);
#pragma unroll
    for (int kf = 0; kf < KF1; ++kf) {
      bf16x8 a[4];
      if (G1) {
#pragma unroll
        for (int rf = 0; rf < 4; ++rf)
          a[rf] = *(const bf16x8*)(At1 + (rf * 16 + lr) * 128 +
                                   ((kf * 32 + lk * 8) ^ ((lr & 7) << 3)));
      } else {
#pragma unroll
        for (int rf = 0; rf < 4; ++rf) a[rf] = *(const bf16x8*)(ap[rf] + kf * 32);
      }
#pragma unroll
      for (int rf = 0; rf < 4; ++rf)
#pragma unroll
        for (int cf = 0; cf < CF; ++cf)
          acc[rf][cf] = __builtin_amdgcn_mfma_f32_16x16x32_bf16(a[rf], B[cf][kf],
                                                                acc[rf][cf], 0, 0, 0);
    }
  }
  // ---- source 2 (always gathered) ----
  if constexpr (K2 > 0) {
    bf16x8 B[CF][KF2];
#pragma unroll
    for (int cf = 0; cf < CF; ++cf)
#pragma unroll
      for (int kf = 0; kf < KF2; ++kf)
        B[cf][kf] = *(const bf16x8*)(F.wt2 + (size_t)(colbase + cf * 16 + lr) * K2 +
                                     kf * 32 + lk * 8);
#pragma unroll
    for (int kf = 0; kf < KF2; ++kf) {
      bf16x8 a[4];
#pragma unroll
      for (int rf = 0; rf < 4; ++rf)
        a[rf] = *(const bf16x8*)(At2 + (rf * 16 + lr) * 128 +
                                 ((kf * 32 + lk * 8) ^ ((lr & 7) << 3)));
#pragma unroll
      for (int rf = 0; rf < 4; ++rf)
#pragma unroll
        for (int cf = 0; cf < CF; ++cf)
          acc[rf][cf] = __builtin_amdgcn_mfma_f32_16x16x32_bf16(a[rf], B[cf][kf],
                                                                acc[rf][cf], 0, 0, 0);
    }
  }

  // ---- epilogue ----
  float bv[CF];
#pragma unroll
  for (int cf = 0; cf < CF; ++cf) bv[cf] = F.bias[colbase + cf * 16 + lr];

  float colS[CF], colQ[CF];
#pragma unroll
  for (int cf = 0; cf < CF; ++cf) { colS[cf] = 0.f; colQ[cf] = 0.f; }

  float* Cf = (float*)F.c;
  unsigned short* Cb = (unsigned short*)F.c;
#pragma unroll
  for (int rf = 0; rf < 4; ++rf) {
#pragma unroll
    for (int r = 0; r < 4; ++r) {
      int row = row0 + rf * 16 + lk * 4 + r;
      bool ok = row < M;
#pragma unroll
      for (int cf = 0; cf < CF; ++cf) {
        int col = colbase + cf * 16 + lr;
        float v = acc[rf][cf][r] + bv[cf];
        if (RELU) v = fmaxf(v, 0.f);
        if (ok) {
          if (OBF16)
            Cb[(size_t)row * NCOLS + col] = f2bf(v);
          else
            Cf[(size_t)row * NCOLS + col] = v;
          if (STATS) { colS[cf] += v; colQ[cf] += v * v; }
        }
      }
    }
  }

  if constexpr (STATS) {
#pragma unroll
    for (int cf = 0; cf < CF; ++cf) {
      float s = colS[cf], q = colQ[cf];
      s += __shfl_xor(s, 16); q += __shfl_xor(q, 16);
      s += __shfl_xor(s, 32); q += __shfl_xor(q, 32);
      if (lk == 0) {
        int col = colbase + cf * 16 + lr;
        atomicAdd(&F.stats[col], s);
        atomicAdd(&F.stats[D + col], q);
      }
    }
  }
}

// ---------------------------------------------------------------------------
__global__ __launch_bounds__(256) void k_bnprep(const float* __restrict__ stats,
                                                const float* __restrict__ gamma,
                                                const float* __restrict__ beta,
                                                float* __restrict__ bnp0,
                                                float* __restrict__ bnp1,
                                                float invM0, float invM1) {
  int i = threadIdx.x;
  if (i < 128) {
    float mu = stats[i] * invM0;
    float var = stats[D + i] * invM0 - mu * mu;
    float sc = rsqrtf(var + BN_EPS) * gamma[i];
    bnp0[i] = sc;
    bnp0[D + i] = beta[i] - mu * sc;
  } else {
    int d = i - 128;
    float mu = stats[2 * D + d] * invM1;
    float var = stats[3 * D + d] * invM1 - mu * mu;
    float sc = rsqrtf(var + BN_EPS) * gamma[d];
    bnp1[d] = sc;
    bnp1[D + d] = beta[d] - mu * sc;
  }
}

// final-layer BN (no relu), fp32 in place
__global__ __launch_bounds__(256) void k_bnfin(float* __restrict__ X, int M,
                                               const float* __restrict__ bnp) {
  int idx = blockIdx.x * 256 + threadIdx.x;
  int i = idx >> 5, c4 = idx & 31;
  if (i >= M) return;
  float4 v = *(float4*)(X + (size_t)i * D + c4 * 4);
  float4 sc = *(const float4*)(bnp + c4 * 4);
  float4 sh = *(const float4*)(bnp + D + c4 * 4);
  float4 o;
  o.x = fmaf(v.x, sc.x, sh.x); o.y = fmaf(v.y, sc.y, sh.y);
  o.z = fmaf(v.z, sc.z, sh.z); o.w = fmaf(v.w, sc.w, sh.w);
  *(float4*)(X + (size_t)i * D + c4 * 4) = o;
}

// ---------------------------------------------------------------------------
extern "C" void kernel_launch(void* const* d_in, const int* in_sizes, int n_in,
                              void* d_out, int out_size, void* d_ws,
                              size_t ws_size, hipStream_t stream) {
  const int* x0 = (const int*)d_in[0];
  const int* x1 = (const int*)d_in[1];
  const int* ei101 = (const int*)d_in[2];
  const int* ea101 = (const int*)d_in[3];
  const int* ei110 = (const int*)d_in[4];
  const int* ea110 = (const int*)d_in[5];
  const int* ei021 = (const int*)d_in[6];
  const int* ea021 = (const int*)d_in[7];
  const int* ei030 = (const int*)d_in[8];
  const int* ea030 = (const int*)d_in[9];
  const float* x_emb1 = (const float*)d_in[10];
  const float* x_emb2 = (const float*)d_in[11];
  const float* e_emb1 = (const float*)d_in[12];
  const float* e_emb2 = (const float*)d_in[13];
  const float* gin_w1 = (const float*)d_in[14];
  const float* gin_b1 = (const float*)d_in[15];
  const float* gin_w2 = (const float*)d_in[16];
  const float* gin_b2 = (const float*)d_in[17];
  const float* w110 = (const float*)d_in[18];
  const float* b110 = (const float*)d_in[19];
  const float* w021 = (const float*)d_in[20];
  const float* b021 = (const float*)d_in[21];
  const float* w030 = (const float*)d_in[22];
  const float* b030 = (const float*)d_in[23];
  const float* bn_gamma = (const float*)d_in[24];
  const float* bn_beta = (const float*)d_in[25];

  int n0 = in_sizes[0] / 2, n1 = in_sizes[1] / 2;
  int E = in_sizes[2] / 2;
  int nmax = n0 > n1 ? n0 : n1;

  float* h0f = (float*)d_out;
  float* h1f = h0f + (size_t)n0 * D;

  // ---- workspace layout ----
  char* p = (char*)d_ws;
  auto alloc = [&](size_t bytes) {
    char* r = p;
    p += (bytes + 63) & ~(size_t)63;
    return r;
  };
  unsigned short* h0r = (unsigned short*)alloc((size_t)n0 * D * 2);  // embeddings
  unsigned short* h1r = (unsigned short*)alloc((size_t)n1 * D * 2);
  unsigned short* h0o = (unsigned short*)alloc((size_t)n0 * D * 2);  // raw layer out
  unsigned short* h1o = (unsigned short*)alloc((size_t)n1 * D * 2);
  unsigned short* hn0 = (unsigned short*)alloc((size_t)n0 * D * 2);  // normalized
  unsigned short* hn1 = (unsigned short*)alloc((size_t)n1 * D * 2);
  unsigned short* hiddenb = (unsigned short*)alloc((size_t)n1 * 256 * 2);
  float* etbl = (float*)alloc(10 * D * 4);
  float* stats = (float*)alloc(4 * D * 4);
  float* bnp0 = (float*)alloc(2 * D * 4);
  float* bnp1 = (float*)alloc(2 * D * 4);
  unsigned short* wt110 = (unsigned short*)alloc(128 * 128 * 2);
  unsigned short* wt030 = (unsigned short*)alloc(128 * 128 * 2);
  unsigned short* wt021 = (unsigned short*)alloc(128 * 128 * 2);
  unsigned short* wtg1 = (unsigned short*)alloc(256 * 128 * 2);  // [N=256][K=128]
  unsigned short* wtg2 = (unsigned short*)alloc(128 * 256 * 2);  // [N=128][K=256]
  float* bias0 = (float*)alloc(128 * 4);
  float* biash = (float*)alloc(256 * 4);
  float* bias1 = (float*)alloc(128 * 4);

  EdgeArr EA;
  CsrPtrs cp;
  const int* eis[4] = {ei101, ei021, ei110, ei030};
  const int* eas[4] = {ea101, ea021, ea110, ea030};
  int ndst[4] = {n1, n1, n0, n0};
  for (int t = 0; t < 4; ++t) {
    cp.rp[t] = (int*)alloc((size_t)(nmax + 1) * 4);
    cp.cur[t] = (int*)alloc((size_t)nmax * 4);
    EA.pay[t] = (int*)alloc((size_t)E * 4);
    cp.n[t] = ndst[t];
    EA.ei[t] = eis[t];
    EA.ea[t] = eas[t];
    EA.cur[t] = cp.cur[t];
  }
  int* bsum = (int*)alloc(4 * MAXNB * 4);

  dim3 b256(256);

  // one-time: tables, embeddings, weight prep, CSR build
  k_etbl<<<5, b256, 0, stream>>>(e_emb1, e_emb2, etbl);
  k_embed<<<(n0 * 32 + 255) / 256, b256, 0, stream>>>(x0, x_emb1, x_emb2, h0r, n0);
  k_embed<<<(n1 * 32 + 255) / 256, b256, 0, stream>>>(x1, x_emb1, x_emb2, h1r, n1);
  k_wprep<<<64, b256, 0, stream>>>(w110, wt110, 128, 128, 0.05f);
  k_wprep<<<64, b256, 0, stream>>>(w030, wt030, 128, 128, 0.05f);
  k_wprep<<<64, b256, 0, stream>>>(w021, wt021, 128, 128, 0.05f);
  k_wprep<<<128, b256, 0, stream>>>(gin_w1, wtg1, 128, 256, 1.0f);
  k_wprep<<<128, b256, 0, stream>>>(gin_w2, wtg2, 256, 128, 0.5f);
  k_bprep<<<1, b256, 0, stream>>>(b110, b030, gin_b1, gin_b2, b021, bias0, biash, bias1);

  for (int t = 0; t < 4; ++t)
    hipMemsetAsync(cp.cur[t], 0, (size_t)ndst[t] * sizeof(int), stream);
  int rsz = (nmax + 7) / 8;
  int nchunks = (E + ECHUNK - 1) / ECHUNK;
  dim3 partGrid(nchunks * 8, 4);
  k_hist_part<<<partGrid, b256, 0, stream>>>(EA, E, rsz);
  hipMemsetAsync(bsum, 0, 4 * MAXNB * sizeof(int), stream);
  int nb = (nmax + 4095) / 4096;
  k_scan1<<<dim3(nb, 4), b256, 0, stream>>>(cp, bsum);
  k_scan2<<<1, dim3(64), 0, stream>>>(bsum);
  k_scan3<<<dim3(nb, 4), b256, 0, stream>>>(cp, bsum, E);
  k_fill_part<<<partGrid, b256, 0, stream>>>(EA, E, rsz);

  int mB0 = (n0 + 63) / 64, mB1 = (n1 + 63) / 64;

  for (int layer = 0; layer < 3; ++layer) {
    // gather sources are READ-ONLY this layer (outputs go to h0o/h1o/d_out)
    const unsigned short* s0 = (layer == 0) ? h0r : hn0;
    const unsigned short* s1 = (layer == 0) ? h1r : hn1;

    hipMemsetAsync(stats, 0, 4 * D * sizeof(float), stream);

    // K1: hidden = relu(gather(z1) @ gin_w1 + gin_b1)
    FArgs Fh = {};
    Fh.hs1 = s1; Fh.rp1 = cp.rp[0]; Fh.pay1 = EA.pay[0]; Fh.mode1 = 2;
    Fh.wt1 = wtg1;
    Fh.etbl = etbl; Fh.bias = biash; Fh.c = hiddenb; Fh.stats = nullptr;
    Fh.M = n1;
    k_fused<256, 128, 0, true, false, true, false, true>
        <<<mB1, b256, 0, stream>>>(Fh);

    // K2: out0 = gather(a110)@wt110 + gather(a030)@wt030 + bias0 (+stats0)
    FArgs F0 = {};
    F0.hs1 = s1; F0.rp1 = cp.rp[2]; F0.pay1 = EA.pay[2]; F0.mode1 = 0;
    F0.wt1 = wt110;
    F0.hs2 = s0; F0.rp2 = cp.rp[3]; F0.pay2 = EA.pay[3]; F0.mode2 = 1;
    F0.wt2 = wt030;
    F0.etbl = etbl; F0.bias = bias0; F0.stats = stats; F0.M = n0;
    // K3: out1 = hidden@wtg2 + gather(a021)@wt021 + bias1 (+stats1)
    FArgs F1 = {};
    F1.a1 = hiddenb; F1.wt1 = wtg2;
    F1.hs2 = s0; F1.rp2 = cp.rp[1]; F1.pay2 = EA.pay[1]; F1.mode2 = 0;
    F1.wt2 = wt021;
    F1.etbl = etbl; F1.bias = bias1; F1.stats = stats + 2 * D; F1.M = n1;

    if (layer < 2) {
      F0.c = h0o;
      k_fused<128, 128, 128, true, true, false, true, true>
          <<<mB0, b256, 0, stream>>>(F0);
      F1.c = h1o;
      k_fused<128, 256, 128, false, true, false, true, true>
          <<<mB1, b256, 0, stream>>>(F1);
    } else {
      F0.c = h0f;
      k_fused<128, 128, 128, true, true, false, true, false>
          <<<mB0, b256, 0, stream>>>(F0);
      F1.c = h1f;
      k_fused<128, 256, 128, false, true, false, true, false>
          <<<mB1, b256, 0, stream>>>(F1);
    }

    k_bnprep<<<1, b256, 0, stream>>>(stats, bn_gamma + layer * D,
                                     bn_beta + layer * D, bnp0, bnp1,
                                     1.0f / n0, 1.0f / n1);
    if (layer < 2) {
      k_hnorm<<<(n0 * 16 + 255) / 256, b256, 0, stream>>>(h0o, hn0, bnp0, n0);
      k_hnorm<<<(n1 * 16 + 255) / 256, b256, 0, stream>>>(h1o, hn1, bnp1, n1);
    } else {
      k_bnfin<<<(n0 * 32 + 255) / 256, b256, 0, stream>>>(h0f, n0, bnp0);
      k_bnfin<<<(n1 * 32 + 255) / 256, b256, 0, stream>>>(h1f, n1, bnp1);
    }
  }
}

// Round 14
// 882.494 us; speedup vs baseline: 1.0410x; 1.0410x over previous
//
#include <hip/hip_runtime.h>

#define D 128
#define BN_EPS 1e-5f
#define MAXNB 16  // max scan blocks per type (n <= 65536)

typedef __attribute__((ext_vector_type(8))) short bf16x8;
typedef __attribute__((ext_vector_type(4))) float f32x4;

__device__ __forceinline__ unsigned short f2bf(float x) {
  unsigned u = __float_as_uint(x);
  u += 0x7FFF + ((u >> 16) & 1);  // round-to-nearest-even
  return (unsigned short)(u >> 16);
}

__device__ __forceinline__ void cvt8(float (&f)[8], bf16x8 r) {
  const unsigned* u = (const unsigned*)&r;
#pragma unroll
  for (int j = 0; j < 4; ++j) {
    f[2 * j] = __uint_as_float(u[j] << 16);
    f[2 * j + 1] = __uint_as_float(u[j] & 0xFFFF0000u);
  }
}

// ---------------------------------------------------------------------------
// edge-attr combo table: 9 combos + self-loop (4,0) at slot 9
__global__ __launch_bounds__(256) void k_etbl(const float* __restrict__ e1,
                                              const float* __restrict__ e2,
                                              float* __restrict__ etbl) {
  int idx = blockIdx.x * 256 + threadIdx.x;
  if (idx < 9 * D) {
    int combo = idx / D, c = idx % D;
    etbl[idx] = e1[(combo / 3) * D + c] + e2[(combo % 3) * D + c];
  } else if (idx < 10 * D) {
    int c = idx - 9 * D;
    etbl[idx] = e1[4 * D + c] + e2[c];
  }
}

// node embedding -> bf16 h
__global__ __launch_bounds__(256) void k_embed(const int* __restrict__ x,
                                               const float* __restrict__ emb1,
                                               const float* __restrict__ emb2,
                                               unsigned short* __restrict__ out,
                                               int n) {
  int idx = blockIdx.x * 256 + threadIdx.x;
  if (idx >= n * 32) return;
  int node = idx >> 5, c4 = idx & 31;
  int i1 = x[2 * node], i2 = x[2 * node + 1];
  float4 v1 = *(const float4*)(emb1 + (size_t)i1 * D + c4 * 4);
  float4 v2 = *(const float4*)(emb2 + (size_t)i2 * D + c4 * 4);
  ushort4 o;
  o.x = f2bf(v1.x + v2.x); o.y = f2bf(v1.y + v2.y);
  o.z = f2bf(v1.z + v2.z); o.w = f2bf(v1.w + v2.w);
  *(ushort4*)(out + (size_t)node * D + c4 * 4) = o;
}

// ---------------------------------------------------------------------------
// weight prep: Wt[n][k] = bf16(W[k][n] * scale)
__global__ __launch_bounds__(256) void k_wprep(const float* __restrict__ W,
                                               unsigned short* __restrict__ Wt,
                                               int K, int N, float scale) {
  int idx = blockIdx.x * 256 + threadIdx.x;
  if (idx >= K * N) return;
  int n = idx / K, k = idx - n * K;
  Wt[idx] = f2bf(W[(size_t)k * N + n] * scale);
}

__global__ __launch_bounds__(256) void k_bprep(
    const float* __restrict__ b110, const float* __restrict__ b030,
    const float* __restrict__ gb1, const float* __restrict__ gb2,
    const float* __restrict__ b021, float* __restrict__ bias0,
    float* __restrict__ biash, float* __restrict__ bias1) {
  int i = threadIdx.x;
  if (i < 128) {
    bias0[i] = 0.05f * (b110[i] + b030[i]);
    bias1[i] = 0.5f * gb2[i] + 0.05f * b021[i];
  }
  biash[i] = gb1[i];
}

// etW[combo][col] = scale * sum_k etbl[combo][k] * W[k][col], combo 0..9
__global__ __launch_bounds__(256) void k_etw(const float* __restrict__ etbl,
                                             const float* __restrict__ W,
                                             float* __restrict__ etw, int N,
                                             float scale) {
  int idx = blockIdx.x * 256 + threadIdx.x;
  if (idx >= 10 * N) return;
  int combo = idx / N, col = idx - combo * N;
  float s = 0.f;
  for (int k = 0; k < 128; ++k) s += etbl[combo * 128 + k] * W[(size_t)k * N + col];
  etw[idx] = s * scale;
}

// fold self-loop es@W into biases (runs after k_bprep + k_etw; idempotent
// across replays because k_bprep rewrites the biases first each launch)
__global__ __launch_bounds__(256) void k_bfix(float* __restrict__ biash,
                                              float* __restrict__ bias0,
                                              const float* __restrict__ etwg1,
                                              const float* __restrict__ etw030) {
  int i = threadIdx.x;
  biash[i] += etwg1[9 * 256 + i];
  if (i < 128) bias0[i] += etw030[9 * 128 + i];
}

// ---------------------------------------------------------------------------
// CSR build, dst-range partitioned
#define ECHUNK 2048
struct EdgeArr {
  const int* ei[4];
  const int* ea[4];
  int* cur[4];
  int* pay[4];
};
struct CsrPtrs {
  int* cur[4];
  int* rp[4];
  int n[4];
};

__global__ __launch_bounds__(256) void k_hist_part(EdgeArr A, int E, int rsz) {
  int t = blockIdx.y;
  int r = blockIdx.x & 7;
  int chunk = blockIdx.x >> 3;
  const int* dstp = A.ei[t] + E;
  int* cur = A.cur[t];
  int lo = r * rsz, hi = lo + rsz;
  int base = chunk * ECHUNK;
  int end = min(base + ECHUNK, E);
  for (int e = base + (int)threadIdx.x; e < end; e += 256) {
    int dst = dstp[e];
    if (dst >= lo && dst < hi) atomicAdd(&cur[dst], 1);
  }
}

__global__ __launch_bounds__(256) void k_scan1(CsrPtrs p, int* __restrict__ bsum) {
  __shared__ int lds[256];
  int type = blockIdx.y;
  const int* cur = p.cur[type];
  int n = p.n[type];
  int base = blockIdx.x * 4096;
  int s = 0;
  for (int i = threadIdx.x; i < 4096; i += 256) {
    int idx = base + i;
    if (idx < n) s += cur[idx];
  }
  int tid = threadIdx.x;
  lds[tid] = s;
  __syncthreads();
  for (int off = 128; off > 0; off >>= 1) {
    if (tid < off) lds[tid] += lds[tid + off];
    __syncthreads();
  }
  if (tid == 0) bsum[type * MAXNB + blockIdx.x] = lds[0];
}

__global__ __launch_bounds__(64) void k_scan2(int* __restrict__ bsum) {
  int t = threadIdx.x;
  if (t < 4) {
    int run = 0;
    for (int i = 0; i < MAXNB; ++i) {
      int v = bsum[t * MAXNB + i];
      bsum[t * MAXNB + i] = run;
      run += v;
    }
  }
}

__global__ __launch_bounds__(256) void k_scan3(CsrPtrs p,
                                               const int* __restrict__ bsum,
                                               int E) {
  __shared__ int lds[256];
  int type = blockIdx.y;
  int* cur = p.cur[type];
  int* rp = p.rp[type];
  int n = p.n[type];
  int tid = threadIdx.x;
  if (blockIdx.x == 0 && tid == 0) rp[n] = E;
  int t0 = blockIdx.x * 4096 + tid * 16;
  int loc[16];
  int s = 0;
#pragma unroll
  for (int j = 0; j < 16; ++j) {
    int idx = t0 + j;
    int v = (idx < n) ? cur[idx] : 0;
    loc[j] = s;
    s += v;
  }
  lds[tid] = s;
  __syncthreads();
  for (int off = 1; off < 256; off <<= 1) {
    int v = (tid >= off) ? lds[tid - off] : 0;
    __syncthreads();
    lds[tid] += v;
    __syncthreads();
  }
  int off0 = bsum[type * MAXNB + blockIdx.x] + ((tid == 0) ? 0 : lds[tid - 1]);
#pragma unroll
  for (int j = 0; j < 16; ++j) {
    int idx = t0 + j;
    if (idx < n) {
      int v = off0 + loc[j];
      rp[idx] = v;
      cur[idx] = v;  // cursor becomes fill position
    }
  }
}

// payload = (combo << 24) | (src * D)  (element offset; src*128 < 2^24)
__global__ __launch_bounds__(256) void k_fill_part(EdgeArr A, int E, int rsz) {
  int t = blockIdx.y;
  int r = blockIdx.x & 7;
  int chunk = blockIdx.x >> 3;
  const int* ei = A.ei[t];
  const int* ea = A.ea[t];
  int* cur = A.cur[t];
  int* pay = A.pay[t];
  int lo = r * rsz, hi = lo + rsz;
  int base = chunk * ECHUNK;
  int end = min(base + ECHUNK, E);
  for (int e = base + (int)threadIdx.x; e < end; e += 256) {
    int dst = ei[E + e];
    if (dst >= lo && dst < hi) {
      int src = ei[e];
      int combo = ea[2 * e] * 3 + ea[2 * e + 1];
      int pos = atomicAdd(&cur[dst], 1);
      pay[pos] = (combo << 24) | (src << 7);
    }
  }
}

// per-node combo counts -> fp32 [node][12] (slots 0..8 used, rest 0)
struct CntArgs {
  const int* rp[4];
  const int* pay[4];
  float* cnt[4];
  int n[4];
};
__global__ __launch_bounds__(256) void k_cnt(CntArgs A) {
  int t = blockIdx.y;
  int g = blockIdx.x * 256 + threadIdx.x;
  if (g >= A.n[t]) return;
  const int* pay = A.pay[t];
  int e0 = A.rp[t][g], e1 = A.rp[t][g + 1];
  float cc[9];
#pragma unroll
  for (int j = 0; j < 9; ++j) cc[j] = 0.f;
  for (int e = e0; e < e1; ++e) {
    int cb = pay[e] >> 24;
#pragma unroll
    for (int j = 0; j < 9; ++j) cc[j] += (cb == j) ? 1.f : 0.f;
  }
  float* o = A.cnt[t] + (size_t)g * 12;
  *(float4*)(o) = make_float4(cc[0], cc[1], cc[2], cc[3]);
  *(float4*)(o + 4) = make_float4(cc[4], cc[5], cc[6], cc[7]);
  *(float4*)(o + 8) = make_float4(cc[8], 0.f, 0.f, 0.f);
}

// ---------------------------------------------------------------------------
// per-layer h normalization: hn = relu(h*sc + sh) in bf16
__global__ __launch_bounds__(256) void k_hnorm(const unsigned short* __restrict__ h,
                                               unsigned short* __restrict__ hn,
                                               const float* __restrict__ bnp,
                                               int n) {
  int idx = blockIdx.x * 256 + threadIdx.x;
  if (idx >= n * 16) return;
  int node = idx >> 4, sl = idx & 15, c = sl * 8;
  bf16x8 v = *(const bf16x8*)(h + (size_t)node * D + c);
  float f[8];
  cvt8(f, v);
  unsigned o[4];
#pragma unroll
  for (int j = 0; j < 4; ++j) {
    float a = fmaxf(fmaf(f[2 * j], bnp[c + 2 * j], bnp[D + c + 2 * j]), 0.f);
    float b = fmaxf(fmaf(f[2 * j + 1], bnp[c + 2 * j + 1], bnp[D + c + 2 * j + 1]), 0.f);
    o[j] = (unsigned)f2bf(a) | ((unsigned)f2bf(b) << 16);
  }
  *(uint4*)(hn + (size_t)node * D + c) = make_uint4(o[0], o[1], o[2], o[3]);
}

// ---------------------------------------------------------------------------
// Merged CSR gather, one WAVE per node: pure row sum (edge-attr contribution
// moved to the GEMM epilogue via cnt x etW). 4 edge-groups x 16 col-lanes,
// 4 nodes/wave, 2-deep unroll. No LDS.
// mode: 0: init=0; 1: init=src[g]; 2: init=2.1*src[g]  (self-loop es in bias)
struct GArgs {
  const unsigned short* src[4];
  const int* rp[4];
  const int* pay[4];
  unsigned short* agg[4];
  int mode[4];
  int n[4];
};

__global__ __launch_bounds__(256) void k_gather_all(GArgs G) {
  int t = blockIdx.y;
  int n = G.n[t];
  int wv = threadIdx.x >> 6;
  int l = threadIdx.x & 63;
  int grp = l >> 4, sl = l & 15, c = sl * 8;
  const unsigned short* __restrict__ hsrc = G.src[t];
  const int* __restrict__ pay = G.pay[t];
  const int* __restrict__ rp = G.rp[t];
  unsigned short* __restrict__ agg = G.agg[t];
  int mode = G.mode[t];
  int gbase = (blockIdx.x * 4 + wv) * 4;

  for (int i = 0; i < 4; ++i) {
    int g = gbase + i;
    if (g >= n) break;
    float acc[8];
    if (grp == 0 && mode != 0) {
      bf16x8 hv = *(const bf16x8*)(hsrc + (size_t)g * D + c);
      float f[8];
      cvt8(f, hv);
      float m = (mode == 2) ? 2.1f : 1.0f;
#pragma unroll
      for (int j = 0; j < 8; ++j) acc[j] = m * f[j];
    } else {
#pragma unroll
      for (int j = 0; j < 8; ++j) acc[j] = 0.f;
    }
    int e1 = rp[g + 1];
    int e = rp[g] + grp;
    while (e + 4 < e1) {
      int p0 = pay[e] & 0xFFFFFF;
      int p1 = pay[e + 4] & 0xFFFFFF;
      bf16x8 r0 = *(const bf16x8*)(hsrc + (size_t)p0 + c);
      bf16x8 r1 = *(const bf16x8*)(hsrc + (size_t)p1 + c);
      float f0[8], f1[8];
      cvt8(f0, r0);
      cvt8(f1, r1);
#pragma unroll
      for (int j = 0; j < 8; ++j) acc[j] += f0[j] + f1[j];
      e += 8;
    }
    if (e < e1) {
      int p0 = pay[e] & 0xFFFFFF;
      bf16x8 r0 = *(const bf16x8*)(hsrc + (size_t)p0 + c);
      float f0[8];
      cvt8(f0, r0);
#pragma unroll
      for (int j = 0; j < 8; ++j) acc[j] += f0[j];
    }
#pragma unroll
    for (int j = 0; j < 8; ++j) {
      acc[j] += __shfl_xor(acc[j], 16);
      acc[j] += __shfl_xor(acc[j], 32);
    }
    if (grp == 0) {
      unsigned o0 = (unsigned)f2bf(acc[0]) | ((unsigned)f2bf(acc[1]) << 16);
      unsigned o1 = (unsigned)f2bf(acc[2]) | ((unsigned)f2bf(acc[3]) << 16);
      unsigned o2 = (unsigned)f2bf(acc[4]) | ((unsigned)f2bf(acc[5]) << 16);
      unsigned o3 = (unsigned)f2bf(acc[6]) | ((unsigned)f2bf(acc[7]) << 16);
      *(uint4*)(agg + (size_t)g * D + c) = make_uint4(o0, o1, o2, o3);
    }
  }
}

// ---------------------------------------------------------------------------
// B-stationary bf16 MFMA GEMM with rank-9 edge-attr correction in epilogue:
// out[row][col] += sum_c cnt[row][c] * etW[c][col]  (fp32 exact).
template <int NCOLS, int K1, int K2, bool RELU, bool STATS, bool OBF16,
          bool C1, bool C2>
__global__ __launch_bounds__(256) void gemm_breg(
    const unsigned short* __restrict__ A1, const unsigned short* __restrict__ Wt1,
    const unsigned short* __restrict__ A2, const unsigned short* __restrict__ Wt2,
    const float* __restrict__ bias, void* __restrict__ Cv, int M,
    float* __restrict__ stats, const float* __restrict__ cnt1,
    const float* __restrict__ etw1, const float* __restrict__ cnt2,
    const float* __restrict__ etw2) {
  constexpr int WC = NCOLS / 4;
  constexpr int CF = WC / 16;
  constexpr int KF1 = K1 / 32;
  constexpr int KF2 = (K2 > 0) ? (K2 / 32) : 1;

  int tid = threadIdx.x;
  int w = tid >> 6, l = tid & 63;
  int lr = l & 15, lk = l >> 4;
  int colbase = w * WC;
  int row0 = blockIdx.x * 64;

  f32x4 acc[4][CF];
#pragma unroll
  for (int rf = 0; rf < 4; ++rf)
#pragma unroll
    for (int cf = 0; cf < CF; ++cf) acc[rf][cf] = (f32x4)(0.f);

  {
    const unsigned short* ap[4];
#pragma unroll
    for (int rf = 0; rf < 4; ++rf) {
      int r = row0 + rf * 16 + lr;
      if (r > M - 1) r = M - 1;
      ap[rf] = A1 + (size_t)r * K1 + lk * 8;
    }
    bf16x8 B[CF][KF1];
#pragma unroll
    for (int cf = 0; cf < CF; ++cf)
#pragma unroll
      for (int kf = 0; kf < KF1; ++kf)
        B[cf][kf] = *(const bf16x8*)(Wt1 + (size_t)(colbase + cf * 16 + lr) * K1 +
                                     kf * 32 + lk * 8);
#pragma unroll
    for (int kf = 0; kf < KF1; ++kf) {
      bf16x8 a[4];
#pragma unroll
      for (int rf = 0; rf < 4; ++rf) a[rf] = *(const bf16x8*)(ap[rf] + kf * 32);
#pragma unroll
      for (int rf = 0; rf < 4; ++rf)
#pragma unroll
        for (int cf = 0; cf < CF; ++cf)
          acc[rf][cf] = __builtin_amdgcn_mfma_f32_16x16x32_bf16(a[rf], B[cf][kf],
                                                                acc[rf][cf], 0, 0, 0);
    }
  }
  if constexpr (K2 > 0) {
    const unsigned short* ap[4];
#pragma unroll
    for (int rf = 0; rf < 4; ++rf) {
      int r = row0 + rf * 16 + lr;
      if (r > M - 1) r = M - 1;
      ap[rf] = A2 + (size_t)r * K2 + lk * 8;
    }
    bf16x8 B[CF][KF2];
#pragma unroll
    for (int cf = 0; cf < CF; ++cf)
#pragma unroll
      for (int kf = 0; kf < KF2; ++kf)
        B[cf][kf] = *(const bf16x8*)(Wt2 + (size_t)(colbase + cf * 16 + lr) * K2 +
                                     kf * 32 + lk * 8);
#pragma unroll
    for (int kf = 0; kf < KF2; ++kf) {
      bf16x8 a[4];
#pragma unroll
      for (int rf = 0; rf < 4; ++rf) a[rf] = *(const bf16x8*)(ap[rf] + kf * 32);
#pragma unroll
      for (int rf = 0; rf < 4; ++rf)
#pragma unroll
        for (int cf = 0; cf < CF; ++cf)
          acc[rf][cf] = __builtin_amdgcn_mfma_f32_16x16x32_bf16(a[rf], B[cf][kf],
                                                                acc[rf][cf], 0, 0, 0);
    }
  }

  float bv[CF];
#pragma unroll
  for (int cf = 0; cf < CF; ++cf) bv[cf] = bias[colbase + cf * 16 + lr];

  float ew1[C1 ? CF : 1][9], ew2[C2 ? CF : 1][9];
  if constexpr (C1) {
#pragma unroll
    for (int cf = 0; cf < CF; ++cf)
#pragma unroll
      for (int cb = 0; cb < 9; ++cb)
        ew1[cf][cb] = etw1[cb * NCOLS + colbase + cf * 16 + lr];
  }
  if constexpr (C2) {
#pragma unroll
    for (int cf = 0; cf < CF; ++cf)
#pragma unroll
      for (int cb = 0; cb < 9; ++cb)
        ew2[cf][cb] = etw2[cb * NCOLS + colbase + cf * 16 + lr];
  }

  float colS[CF], colQ[CF];
#pragma unroll
  for (int cf = 0; cf < CF; ++cf) { colS[cf] = 0.f; colQ[cf] = 0.f; }

  float* Cf = (float*)Cv;
  unsigned short* Cb = (unsigned short*)Cv;
#pragma unroll
  for (int rf = 0; rf < 4; ++rf) {
#pragma unroll
    for (int r = 0; r < 4; ++r) {
      int row = row0 + rf * 16 + lk * 4 + r;
      bool ok = row < M;
      int crow = ok ? row : 0;
      float cv1[9], cv2[9];
      if constexpr (C1) {
        float4 a = *(const float4*)(cnt1 + (size_t)crow * 12);
        float4 b = *(const float4*)(cnt1 + (size_t)crow * 12 + 4);
        float4 cc = *(const float4*)(cnt1 + (size_t)crow * 12 + 8);
        cv1[0] = a.x; cv1[1] = a.y; cv1[2] = a.z; cv1[3] = a.w;
        cv1[4] = b.x; cv1[5] = b.y; cv1[6] = b.z; cv1[7] = b.w;
        cv1[8] = cc.x;
      }
      if constexpr (C2) {
        float4 a = *(const float4*)(cnt2 + (size_t)crow * 12);
        float4 b = *(const float4*)(cnt2 + (size_t)crow * 12 + 4);
        float4 cc = *(const float4*)(cnt2 + (size_t)crow * 12 + 8);
        cv2[0] = a.x; cv2[1] = a.y; cv2[2] = a.z; cv2[3] = a.w;
        cv2[4] = b.x; cv2[5] = b.y; cv2[6] = b.z; cv2[7] = b.w;
        cv2[8] = cc.x;
      }
#pragma unroll
      for (int cf = 0; cf < CF; ++cf) {
        int col = colbase + cf * 16 + lr;
        float v = acc[rf][cf][r] + bv[cf];
        if constexpr (C1) {
#pragma unroll
          for (int cb = 0; cb < 9; ++cb) v = fmaf(cv1[cb], ew1[cf][cb], v);
        }
        if constexpr (C2) {
#pragma unroll
          for (int cb = 0; cb < 9; ++cb) v = fmaf(cv2[cb], ew2[cf][cb], v);
        }
        if (RELU) v = fmaxf(v, 0.f);
        if (ok) {
          if (OBF16)
            Cb[(size_t)row * NCOLS + col] = f2bf(v);
          else
            Cf[(size_t)row * NCOLS + col] = v;
          if (STATS) { colS[cf] += v; colQ[cf] += v * v; }
        }
      }
    }
  }

  if constexpr (STATS) {
#pragma unroll
    for (int cf = 0; cf < CF; ++cf) {
      float s = colS[cf], q = colQ[cf];
      s += __shfl_xor(s, 16); q += __shfl_xor(q, 16);
      s += __shfl_xor(s, 32); q += __shfl_xor(q, 32);
      if (lk == 0) {
        int col = colbase + cf * 16 + lr;
        atomicAdd(&stats[col], s);
        atomicAdd(&stats[D + col], q);
      }
    }
  }
}

// ---------------------------------------------------------------------------
__global__ __launch_bounds__(256) void k_bnprep(const float* __restrict__ stats,
                                                const float* __restrict__ gamma,
                                                const float* __restrict__ beta,
                                                float* __restrict__ bnp0,
                                                float* __restrict__ bnp1,
                                                float invM0, float invM1) {
  int i = threadIdx.x;
  if (i < 128) {
    float mu = stats[i] * invM0;
    float var = stats[D + i] * invM0 - mu * mu;
    float sc = rsqrtf(var + BN_EPS) * gamma[i];
    bnp0[i] = sc;
    bnp0[D + i] = beta[i] - mu * sc;
  } else {
    int d = i - 128;
    float mu = stats[2 * D + d] * invM1;
    float var = stats[3 * D + d] * invM1 - mu * mu;
    float sc = rsqrtf(var + BN_EPS) * gamma[d];
    bnp1[d] = sc;
    bnp1[D + d] = beta[d] - mu * sc;
  }
}

// final-layer BN (no relu), fp32 in place
__global__ __launch_bounds__(256) void k_bnfin(float* __restrict__ X, int M,
                                               const float* __restrict__ bnp) {
  int idx = blockIdx.x * 256 + threadIdx.x;
  int i = idx >> 5, c4 = idx & 31;
  if (i >= M) return;
  float4 v = *(float4*)(X + (size_t)i * D + c4 * 4);
  float4 sc = *(const float4*)(bnp + c4 * 4);
  float4 sh = *(const float4*)(bnp + D + c4 * 4);
  float4 o;
  o.x = fmaf(v.x, sc.x, sh.x); o.y = fmaf(v.y, sc.y, sh.y);
  o.z = fmaf(v.z, sc.z, sh.z); o.w = fmaf(v.w, sc.w, sh.w);
  *(float4*)(X + (size_t)i * D + c4 * 4) = o;
}

// ---------------------------------------------------------------------------
extern "C" void kernel_launch(void* const* d_in, const int* in_sizes, int n_in,
                              void* d_out, int out_size, void* d_ws,
                              size_t ws_size, hipStream_t stream) {
  const int* x0 = (const int*)d_in[0];
  const int* x1 = (const int*)d_in[1];
  const int* ei101 = (const int*)d_in[2];
  const int* ea101 = (const int*)d_in[3];
  const int* ei110 = (const int*)d_in[4];
  const int* ea110 = (const int*)d_in[5];
  const int* ei021 = (const int*)d_in[6];
  const int* ea021 = (const int*)d_in[7];
  const int* ei030 = (const int*)d_in[8];
  const int* ea030 = (const int*)d_in[9];
  const float* x_emb1 = (const float*)d_in[10];
  const float* x_emb2 = (const float*)d_in[11];
  const float* e_emb1 = (const float*)d_in[12];
  const float* e_emb2 = (const float*)d_in[13];
  const float* gin_w1 = (const float*)d_in[14];
  const float* gin_b1 = (const float*)d_in[15];
  const float* gin_w2 = (const float*)d_in[16];
  const float* gin_b2 = (const float*)d_in[17];
  const float* w110 = (const float*)d_in[18];
  const float* b110 = (const float*)d_in[19];
  const float* w021 = (const float*)d_in[20];
  const float* b021 = (const float*)d_in[21];
  const float* w030 = (const float*)d_in[22];
  const float* b030 = (const float*)d_in[23];
  const float* bn_gamma = (const float*)d_in[24];
  const float* bn_beta = (const float*)d_in[25];

  int n0 = in_sizes[0] / 2, n1 = in_sizes[1] / 2;
  int E = in_sizes[2] / 2;
  int nmax = n0 > n1 ? n0 : n1;

  float* h0f = (float*)d_out;
  float* h1f = h0f + (size_t)n0 * D;

  // ---- workspace layout ----
  char* p = (char*)d_ws;
  auto alloc = [&](size_t bytes) {
    char* r = p;
    p += (bytes + 63) & ~(size_t)63;
    return r;
  };
  unsigned short* h0r = (unsigned short*)alloc((size_t)n0 * D * 2);
  unsigned short* h1r = (unsigned short*)alloc((size_t)n1 * D * 2);
  unsigned short* hn0 = (unsigned short*)alloc((size_t)n0 * D * 2);
  unsigned short* hn1 = (unsigned short*)alloc((size_t)n1 * D * 2);
  unsigned short* z1b = (unsigned short*)alloc((size_t)n1 * D * 2);
  unsigned short* a021b = (unsigned short*)alloc((size_t)n1 * D * 2);
  unsigned short* a110b = (unsigned short*)alloc((size_t)n0 * D * 2);
  unsigned short* a030b = (unsigned short*)alloc((size_t)n0 * D * 2);
  unsigned short* hiddenb = (unsigned short*)alloc((size_t)n1 * 256 * 2);
  float* etbl = (float*)alloc(10 * D * 4);
  float* stats = (float*)alloc(4 * D * 4);
  float* bnp0 = (float*)alloc(2 * D * 4);
  float* bnp1 = (float*)alloc(2 * D * 4);
  unsigned short* wt110 = (unsigned short*)alloc(128 * 128 * 2);
  unsigned short* wt030 = (unsigned short*)alloc(128 * 128 * 2);
  unsigned short* wt021 = (unsigned short*)alloc(128 * 128 * 2);
  unsigned short* wtg1 = (unsigned short*)alloc(256 * 128 * 2);  // [N=256][K=128]
  unsigned short* wtg2 = (unsigned short*)alloc(128 * 256 * 2);  // [N=128][K=256]
  float* bias0 = (float*)alloc(128 * 4);
  float* biash = (float*)alloc(256 * 4);
  float* bias1 = (float*)alloc(128 * 4);
  float* etwg1 = (float*)alloc(10 * 256 * 4);
  float* etw021 = (float*)alloc(10 * 128 * 4);
  float* etw110 = (float*)alloc(10 * 128 * 4);
  float* etw030 = (float*)alloc(10 * 128 * 4);

  EdgeArr EA;
  CsrPtrs cp;
  CntArgs CA;
  const int* eis[4] = {ei101, ei021, ei110, ei030};
  const int* eas[4] = {ea101, ea021, ea110, ea030};
  int ndst[4] = {n1, n1, n0, n0};
  for (int t = 0; t < 4; ++t) {
    cp.rp[t] = (int*)alloc((size_t)(nmax + 1) * 4);
    cp.cur[t] = (int*)alloc((size_t)nmax * 4);
    EA.pay[t] = (int*)alloc((size_t)E * 4);
    CA.cnt[t] = (float*)alloc((size_t)nmax * 12 * 4);
    cp.n[t] = ndst[t];
    EA.ei[t] = eis[t];
    EA.ea[t] = eas[t];
    EA.cur[t] = cp.cur[t];
    CA.rp[t] = cp.rp[t];
    CA.pay[t] = EA.pay[t];
    CA.n[t] = ndst[t];
  }
  int* bsum = (int*)alloc(4 * MAXNB * 4);

  dim3 b256(256);

  // one-time: tables, embeddings, weight prep, CSR build, cnt, etW
  k_etbl<<<5, b256, 0, stream>>>(e_emb1, e_emb2, etbl);
  k_embed<<<(n0 * 32 + 255) / 256, b256, 0, stream>>>(x0, x_emb1, x_emb2, h0r, n0);
  k_embed<<<(n1 * 32 + 255) / 256, b256, 0, stream>>>(x1, x_emb1, x_emb2, h1r, n1);
  k_wprep<<<64, b256, 0, stream>>>(w110, wt110, 128, 128, 0.05f);
  k_wprep<<<64, b256, 0, stream>>>(w030, wt030, 128, 128, 0.05f);
  k_wprep<<<64, b256, 0, stream>>>(w021, wt021, 128, 128, 0.05f);
  k_wprep<<<128, b256, 0, stream>>>(gin_w1, wtg1, 128, 256, 1.0f);
  k_wprep<<<128, b256, 0, stream>>>(gin_w2, wtg2, 256, 128, 0.5f);
  k_bprep<<<1, b256, 0, stream>>>(b110, b030, gin_b1, gin_b2, b021, bias0, biash, bias1);
  k_etw<<<10, b256, 0, stream>>>(etbl, gin_w1, etwg1, 256, 1.0f);
  k_etw<<<5, b256, 0, stream>>>(etbl, w021, etw021, 128, 0.05f);
  k_etw<<<5, b256, 0, stream>>>(etbl, w110, etw110, 128, 0.05f);
  k_etw<<<5, b256, 0, stream>>>(etbl, w030, etw030, 128, 0.05f);
  k_bfix<<<1, b256, 0, stream>>>(biash, bias0, etwg1, etw030);

  for (int t = 0; t < 4; ++t)
    hipMemsetAsync(cp.cur[t], 0, (size_t)ndst[t] * sizeof(int), stream);
  int rsz = (nmax + 7) / 8;
  int nchunks = (E + ECHUNK - 1) / ECHUNK;
  dim3 partGrid(nchunks * 8, 4);
  k_hist_part<<<partGrid, b256, 0, stream>>>(EA, E, rsz);
  hipMemsetAsync(bsum, 0, 4 * MAXNB * sizeof(int), stream);
  int nb = (nmax + 4095) / 4096;
  k_scan1<<<dim3(nb, 4), b256, 0, stream>>>(cp, bsum);
  k_scan2<<<1, dim3(64), 0, stream>>>(bsum);
  k_scan3<<<dim3(nb, 4), b256, 0, stream>>>(cp, bsum, E);
  k_fill_part<<<partGrid, b256, 0, stream>>>(EA, E, rsz);
  k_cnt<<<dim3((nmax + 255) / 256, 4), b256, 0, stream>>>(CA);

  // merged gather args (types: z1, a021, a110, a030)
  GArgs GA;
  GA.agg[0] = z1b;   GA.mode[0] = 2; GA.n[0] = n1;
  GA.agg[1] = a021b; GA.mode[1] = 0; GA.n[1] = n1;
  GA.agg[2] = a110b; GA.mode[2] = 0; GA.n[2] = n0;
  GA.agg[3] = a030b; GA.mode[3] = 1; GA.n[3] = n0;
  for (int t = 0; t < 4; ++t) {
    GA.rp[t] = cp.rp[t];
    GA.pay[t] = EA.pay[t];
  }

  int mB0 = (n0 + 63) / 64, mB1 = (n1 + 63) / 64;
  dim3 gGrid((nmax + 15) / 16, 4);

  for (int layer = 0; layer < 3; ++layer) {
    const unsigned short* s0 = (layer == 0) ? h0r : hn0;
    const unsigned short* s1 = (layer == 0) ? h1r : hn1;
    GA.src[0] = s1; GA.src[1] = s0; GA.src[2] = s1; GA.src[3] = s0;
    k_gather_all<<<gGrid, b256, 0, stream>>>(GA);

    hipMemsetAsync(stats, 0, 4 * D * sizeof(float), stream);

    if (layer < 2) {
      // out0 = a110@wt110 + a030@wt030 + bias0 + corr(cnt110,cnt030)
      gemm_breg<128, 128, 128, false, true, true, true, true>
          <<<mB0, b256, 0, stream>>>(a110b, wt110, a030b, wt030, bias0, h0r, n0,
                                     stats, CA.cnt[2], etw110, CA.cnt[3], etw030);
      // hidden = relu(z1@gin_w1 + biash + corr(cnt101))
      gemm_breg<256, 128, 0, true, false, true, true, false>
          <<<mB1, b256, 0, stream>>>(z1b, wtg1, nullptr, nullptr, biash, hiddenb,
                                     n1, nullptr, CA.cnt[0], etwg1, nullptr, nullptr);
      // out1 = hidden@wtg2 + a021@wt021 + bias1 + corr(cnt021)
      gemm_breg<128, 256, 128, false, true, true, false, true>
          <<<mB1, b256, 0, stream>>>(hiddenb, wtg2, a021b, wt021, bias1, h1r, n1,
                                     stats + 2 * D, nullptr, nullptr, CA.cnt[1], etw021);
    } else {
      gemm_breg<128, 128, 128, false, true, false, true, true>
          <<<mB0, b256, 0, stream>>>(a110b, wt110, a030b, wt030, bias0, h0f, n0,
                                     stats, CA.cnt[2], etw110, CA.cnt[3], etw030);
      gemm_breg<256, 128, 0, true, false, true, true, false>
          <<<mB1, b256, 0, stream>>>(z1b, wtg1, nullptr, nullptr, biash, hiddenb,
                                     n1, nullptr, CA.cnt[0], etwg1, nullptr, nullptr);
      gemm_breg<128, 256, 128, false, true, false, false, true>
          <<<mB1, b256, 0, stream>>>(hiddenb, wtg2, a021b, wt021, bias1, h1f, n1,
                                     stats + 2 * D, nullptr, nullptr, CA.cnt[1], etw021);
    }

    k_bnprep<<<1, b256, 0, stream>>>(stats, bn_gamma + layer * D,
                                     bn_beta + layer * D, bnp0, bnp1,
                                     1.0f / n0, 1.0f / n1);
    if (layer < 2) {
      k_hnorm<<<(n0 * 16 + 255) / 256, b256, 0, stream>>>(h0r, hn0, bnp0, n0);
      k_hnorm<<<(n1 * 16 + 255) / 256, b256, 0, stream>>>(h1r, hn1, bnp1, n1);
    } else {
      k_bnfin<<<(n0 * 32 + 255) / 256, b256, 0, stream>>>(h0f, n0, bnp0);
      k_bnfin<<<(n1 * 32 + 255) / 256, b256, 0, stream>>>(h1f, n1, bnp1);
    }
  }
}

// Round 15
// 777.676 us; speedup vs baseline: 1.1813x; 1.1348x over previous
//
#include <hip/hip_runtime.h>

#define D 128
#define BN_EPS 1e-5f
#define MAXNB 16  // max scan blocks per type (n <= 65536)
#define ECHUNK 2048

typedef __attribute__((ext_vector_type(8))) short bf16x8;
typedef __attribute__((ext_vector_type(4))) float f32x4;

__device__ __forceinline__ unsigned short f2bf(float x) {
  unsigned u = __float_as_uint(x);
  u += 0x7FFF + ((u >> 16) & 1);  // round-to-nearest-even
  return (unsigned short)(u >> 16);
}
__device__ __forceinline__ float bf2f(unsigned short u) {
  return __uint_as_float((unsigned)u << 16);
}

// ---------------------------------------------------------------------------
// edge-attr combo table: 9 combos + self-loop (4,0) at slot 9
__global__ __launch_bounds__(256) void k_etbl(const float* __restrict__ e1,
                                              const float* __restrict__ e2,
                                              float* __restrict__ etbl) {
  int idx = blockIdx.x * 256 + threadIdx.x;
  if (idx < 9 * D) {
    int combo = idx / D, c = idx % D;
    etbl[idx] = e1[(combo / 3) * D + c] + e2[(combo % 3) * D + c];
  } else if (idx < 10 * D) {
    int c = idx - 9 * D;
    etbl[idx] = e1[4 * D + c] + e2[c];
  }
}

// node embedding -> bf16 h
__global__ __launch_bounds__(256) void k_embed(const int* __restrict__ x,
                                               const float* __restrict__ emb1,
                                               const float* __restrict__ emb2,
                                               unsigned short* __restrict__ out,
                                               int n) {
  int idx = blockIdx.x * 256 + threadIdx.x;
  if (idx >= n * 32) return;
  int node = idx >> 5, c4 = idx & 31;
  int i1 = x[2 * node], i2 = x[2 * node + 1];
  float4 v1 = *(const float4*)(emb1 + (size_t)i1 * D + c4 * 4);
  float4 v2 = *(const float4*)(emb2 + (size_t)i2 * D + c4 * 4);
  ushort4 o;
  o.x = f2bf(v1.x + v2.x); o.y = f2bf(v1.y + v2.y);
  o.z = f2bf(v1.z + v2.z); o.w = f2bf(v1.w + v2.w);
  *(ushort4*)(out + (size_t)node * D + c4 * 4) = o;
}

// ---------------------------------------------------------------------------
// weight prep: Wt[n][k] = bf16(W[k][n] * scale)
__global__ __launch_bounds__(256) void k_wprep(const float* __restrict__ W,
                                               unsigned short* __restrict__ Wt,
                                               int K, int N, float scale) {
  int idx = blockIdx.x * 256 + threadIdx.x;
  if (idx >= K * N) return;
  int n = idx / K, k = idx - n * K;
  Wt[idx] = f2bf(W[(size_t)k * N + n] * scale);
}

__global__ __launch_bounds__(256) void k_bprep(
    const float* __restrict__ b110, const float* __restrict__ b030,
    const float* __restrict__ gb1, const float* __restrict__ gb2,
    const float* __restrict__ b021, float* __restrict__ bias0,
    float* __restrict__ biash, float* __restrict__ bias1) {
  int i = threadIdx.x;
  if (i < 128) {
    bias0[i] = 0.05f * (b110[i] + b030[i]);
    bias1[i] = 0.5f * gb2[i] + 0.05f * b021[i];
  }
  biash[i] = gb1[i];
}

// ---------------------------------------------------------------------------
// CSR build, dst-range partitioned (range r = blockIdx.x & 7 tracks the XCD
// round-robin so each cursor/payload region is written from ~one XCD)
struct EdgeArr {
  const int* ei[4];
  const int* ea[4];
  int* cur[4];
  int* pay[4];
};
struct CsrPtrs {
  int* cur[4];
  int* rp[4];
  int n[4];
};

__global__ __launch_bounds__(256) void k_hist_part(EdgeArr A, int E, int rsz) {
  int t = blockIdx.y;
  int r = blockIdx.x & 7;
  int chunk = blockIdx.x >> 3;
  const int* dstp = A.ei[t] + E;
  int* cur = A.cur[t];
  int lo = r * rsz, hi = lo + rsz;
  int base = chunk * ECHUNK;
  int end = min(base + ECHUNK, E);
  for (int e = base + (int)threadIdx.x; e < end; e += 256) {
    int dst = dstp[e];
    if (dst >= lo && dst < hi) atomicAdd(&cur[dst], 1);
  }
}

__global__ __launch_bounds__(256) void k_scan1(CsrPtrs p, int* __restrict__ bsum) {
  __shared__ int lds[256];
  int type = blockIdx.y;
  const int* cur = p.cur[type];
  int n = p.n[type];
  int base = blockIdx.x * 4096;
  int s = 0;
  for (int i = threadIdx.x; i < 4096; i += 256) {
    int idx = base + i;
    if (idx < n) s += cur[idx];
  }
  int tid = threadIdx.x;
  lds[tid] = s;
  __syncthreads();
  for (int off = 128; off > 0; off >>= 1) {
    if (tid < off) lds[tid] += lds[tid + off];
    __syncthreads();
  }
  if (tid == 0) bsum[type * MAXNB + blockIdx.x] = lds[0];
}

__global__ __launch_bounds__(64) void k_scan2(int* __restrict__ bsum) {
  int t = threadIdx.x;
  if (t < 4) {
    int run = 0;
    for (int i = 0; i < MAXNB; ++i) {
      int v = bsum[t * MAXNB + i];
      bsum[t * MAXNB + i] = run;
      run += v;
    }
  }
}

__global__ __launch_bounds__(256) void k_scan3(CsrPtrs p,
                                               const int* __restrict__ bsum,
                                               int E) {
  __shared__ int lds[256];
  int type = blockIdx.y;
  int* cur = p.cur[type];
  int* rp = p.rp[type];
  int n = p.n[type];
  int tid = threadIdx.x;
  if (blockIdx.x == 0 && tid == 0) rp[n] = E;
  int t0 = blockIdx.x * 4096 + tid * 16;
  int loc[16];
  int s = 0;
#pragma unroll
  for (int j = 0; j < 16; ++j) {
    int idx = t0 + j;
    int v = (idx < n) ? cur[idx] : 0;
    loc[j] = s;
    s += v;
  }
  lds[tid] = s;
  __syncthreads();
  for (int off = 1; off < 256; off <<= 1) {
    int v = (tid >= off) ? lds[tid - off] : 0;
    __syncthreads();
    lds[tid] += v;
    __syncthreads();
  }
  int off0 = bsum[type * MAXNB + blockIdx.x] + ((tid == 0) ? 0 : lds[tid - 1]);
#pragma unroll
  for (int j = 0; j < 16; ++j) {
    int idx = t0 + j;
    if (idx < n) {
      int v = off0 + loc[j];
      rp[idx] = v;
      cur[idx] = v;  // cursor becomes fill position
    }
  }
}

// payload = src | (combo << 16), dst-range partitioned
__global__ __launch_bounds__(256) void k_fill_part(EdgeArr A, int E, int rsz) {
  int t = blockIdx.y;
  int r = blockIdx.x & 7;
  int chunk = blockIdx.x >> 3;
  const int* ei = A.ei[t];
  const int* ea = A.ea[t];
  int* cur = A.cur[t];
  int* pay = A.pay[t];
  int lo = r * rsz, hi = lo + rsz;
  int base = chunk * ECHUNK;
  int end = min(base + ECHUNK, E);
  for (int e = base + (int)threadIdx.x; e < end; e += 256) {
    int dst = ei[E + e];
    if (dst >= lo && dst < hi) {
      int src = ei[e];
      int combo = ea[2 * e] * 3 + ea[2 * e + 1];
      int pos = atomicAdd(&cur[dst], 1);
      pay[pos] = src | (combo << 16);
    }
  }
}

// ---------------------------------------------------------------------------
// Merged CSR gather: all 4 edge types in one dispatch (grid.y = type).
// 16 lanes/node, bf16x8 (16B) loads, 4-deep unrolled edge loop for MLP.
// mode: 0: init=0; 1: init=h~(g)+es; 2: init=2.1*h~(g)+es
// norm: h~ = relu(h*sc+sh) applied on read (layers 1,2), else h~ = h.
struct GArgs {
  const unsigned short* src[4];
  const unsigned short* ini[4];
  const float* bnp[4];
  const int* rp[4];
  const int* pay[4];
  unsigned short* agg[4];
  int mode[4];
  int n[4];
  int norm;
};

__device__ __forceinline__ void cvt8(float (&f)[8], bf16x8 r) {
  const unsigned* u = (const unsigned*)&r;
#pragma unroll
  for (int j = 0; j < 4; ++j) {
    f[2 * j] = __uint_as_float(u[j] << 16);
    f[2 * j + 1] = __uint_as_float(u[j] & 0xFFFF0000u);
  }
}

__device__ __forceinline__ void addrow(float (&acc)[8], bf16x8 r,
                                       const float* etp, const float (&sc)[8],
                                       const float (&sh)[8], bool norm) {
  float f[8];
  cvt8(f, r);
  if (norm) {
#pragma unroll
    for (int j = 0; j < 8; ++j) f[j] = fmaxf(fmaf(f[j], sc[j], sh[j]), 0.f);
  }
  float4 ea = *(const float4*)etp;
  float4 eb = *(const float4*)(etp + 4);
  acc[0] += f[0] + ea.x; acc[1] += f[1] + ea.y;
  acc[2] += f[2] + ea.z; acc[3] += f[3] + ea.w;
  acc[4] += f[4] + eb.x; acc[5] += f[5] + eb.y;
  acc[6] += f[6] + eb.z; acc[7] += f[7] + eb.w;
}

__global__ __launch_bounds__(256) void k_gather_all(GArgs G,
                                                    const float* __restrict__ etbl) {
  __shared__ float et[10 * D];
  for (int i = threadIdx.x; i < 10 * D; i += 256) et[i] = etbl[i];
  __syncthreads();
  int t = blockIdx.y;
  int g = blockIdx.x * 16 + (threadIdx.x >> 4);
  if (g >= G.n[t]) return;
  int l = threadIdx.x & 15;
  int c = l * 8;
  const unsigned short* __restrict__ hsrc = G.src[t];
  const int* __restrict__ pay = G.pay[t];
  bool norm = G.norm != 0;

  float sc[8], sh[8];
  if (norm) {
    const float* bnp = G.bnp[t];
#pragma unroll
    for (int j = 0; j < 8; ++j) { sc[j] = bnp[c + j]; sh[j] = bnp[D + c + j]; }
  } else {
#pragma unroll
    for (int j = 0; j < 8; ++j) { sc[j] = 1.f; sh[j] = 0.f; }
  }

  float acc[8];
  int mode = G.mode[t];
  if (mode == 0) {
#pragma unroll
    for (int j = 0; j < 8; ++j) acc[j] = 0.f;
  } else {
    bf16x8 hv = *(const bf16x8*)(G.ini[t] + (size_t)g * D + c);
    float f[8];
    cvt8(f, hv);
    if (norm) {
#pragma unroll
      for (int j = 0; j < 8; ++j) f[j] = fmaxf(fmaf(f[j], sc[j], sh[j]), 0.f);
    }
    float m = (mode == 2) ? 2.1f : 1.0f;
#pragma unroll
    for (int j = 0; j < 8; ++j) acc[j] = m * f[j] + et[9 * D + c + j];
  }

  int e0 = G.rp[t][g], e1 = G.rp[t][g + 1];
  int e = e0;
  while (e < e1) {
    int cnt = min(16, e1 - e);
    int pv = (e + l < e1) ? pay[e + l] : 0;  // coalesced 16-edge chunk
    int j = 0;
    for (; j + 3 < cnt; j += 4) {
      int p0 = __shfl(pv, j, 16);
      int p1 = __shfl(pv, j + 1, 16);
      int p2 = __shfl(pv, j + 2, 16);
      int p3 = __shfl(pv, j + 3, 16);
      bf16x8 r0 = *(const bf16x8*)(hsrc + (size_t)(p0 & 0xFFFF) * D + c);
      bf16x8 r1 = *(const bf16x8*)(hsrc + (size_t)(p1 & 0xFFFF) * D + c);
      bf16x8 r2 = *(const bf16x8*)(hsrc + (size_t)(p2 & 0xFFFF) * D + c);
      bf16x8 r3 = *(const bf16x8*)(hsrc + (size_t)(p3 & 0xFFFF) * D + c);
      addrow(acc, r0, et + (p0 >> 16) * D + c, sc, sh, norm);
      addrow(acc, r1, et + (p1 >> 16) * D + c, sc, sh, norm);
      addrow(acc, r2, et + (p2 >> 16) * D + c, sc, sh, norm);
      addrow(acc, r3, et + (p3 >> 16) * D + c, sc, sh, norm);
    }
    for (; j < cnt; ++j) {
      int p0 = __shfl(pv, j, 16);
      bf16x8 r0 = *(const bf16x8*)(hsrc + (size_t)(p0 & 0xFFFF) * D + c);
      addrow(acc, r0, et + (p0 >> 16) * D + c, sc, sh, norm);
    }
    e += cnt;
  }

  unsigned o0 = (unsigned)f2bf(acc[0]) | ((unsigned)f2bf(acc[1]) << 16);
  unsigned o1 = (unsigned)f2bf(acc[2]) | ((unsigned)f2bf(acc[3]) << 16);
  unsigned o2 = (unsigned)f2bf(acc[4]) | ((unsigned)f2bf(acc[5]) << 16);
  unsigned o3 = (unsigned)f2bf(acc[6]) | ((unsigned)f2bf(acc[7]) << 16);
  *(uint4*)(G.agg[t] + (size_t)g * D + c) = make_uint4(o0, o1, o2, o3);
}

// ---------------------------------------------------------------------------
// B-stationary bf16 MFMA GEMM.
// Block = 256 thr (4 waves), tile 64 rows x NCOLS. Wave w: all 64 rows x
// NCOLS/4 cols, whole B panel in registers (loaded once from L2).
template <int NCOLS, int K1, int K2, bool RELU, bool STATS, bool OBF16>
__global__ __launch_bounds__(256) void gemm_breg(
    const unsigned short* __restrict__ A1, const unsigned short* __restrict__ Wt1,
    const unsigned short* __restrict__ A2, const unsigned short* __restrict__ Wt2,
    const float* __restrict__ bias, void* __restrict__ Cv, int M,
    float* __restrict__ stats) {
  constexpr int WC = NCOLS / 4;
  constexpr int CF = WC / 16;
  constexpr int KF1 = K1 / 32;
  constexpr int KF2 = (K2 > 0) ? (K2 / 32) : 1;

  int tid = threadIdx.x;
  int w = tid >> 6, l = tid & 63;
  int lr = l & 15, lk = l >> 4;
  int colbase = w * WC;
  int row0 = blockIdx.x * 64;

  f32x4 acc[4][CF];
#pragma unroll
  for (int rf = 0; rf < 4; ++rf)
#pragma unroll
    for (int cf = 0; cf < CF; ++cf) acc[rf][cf] = (f32x4)(0.f);

  {
    const unsigned short* ap[4];
#pragma unroll
    for (int rf = 0; rf < 4; ++rf) {
      int r = row0 + rf * 16 + lr;
      if (r > M - 1) r = M - 1;
      ap[rf] = A1 + (size_t)r * K1 + lk * 8;
    }
    bf16x8 B[CF][KF1];
#pragma unroll
    for (int cf = 0; cf < CF; ++cf)
#pragma unroll
      for (int kf = 0; kf < KF1; ++kf)
        B[cf][kf] = *(const bf16x8*)(Wt1 + (size_t)(colbase + cf * 16 + lr) * K1 +
                                     kf * 32 + lk * 8);
#pragma unroll
    for (int kf = 0; kf < KF1; ++kf) {
      bf16x8 a[4];
#pragma unroll
      for (int rf = 0; rf < 4; ++rf) a[rf] = *(const bf16x8*)(ap[rf] + kf * 32);
#pragma unroll
      for (int rf = 0; rf < 4; ++rf)
#pragma unroll
        for (int cf = 0; cf < CF; ++cf)
          acc[rf][cf] = __builtin_amdgcn_mfma_f32_16x16x32_bf16(a[rf], B[cf][kf],
                                                                acc[rf][cf], 0, 0, 0);
    }
  }
  if constexpr (K2 > 0) {
    const unsigned short* ap[4];
#pragma unroll
    for (int rf = 0; rf < 4; ++rf) {
      int r = row0 + rf * 16 + lr;
      if (r > M - 1) r = M - 1;
      ap[rf] = A2 + (size_t)r * K2 + lk * 8;
    }
    bf16x8 B[CF][KF2];
#pragma unroll
    for (int cf = 0; cf < CF; ++cf)
#pragma unroll
      for (int kf = 0; kf < KF2; ++kf)
        B[cf][kf] = *(const bf16x8*)(Wt2 + (size_t)(colbase + cf * 16 + lr) * K2 +
                                     kf * 32 + lk * 8);
#pragma unroll
    for (int kf = 0; kf < KF2; ++kf) {
      bf16x8 a[4];
#pragma unroll
      for (int rf = 0; rf < 4; ++rf) a[rf] = *(const bf16x8*)(ap[rf] + kf * 32);
#pragma unroll
      for (int rf = 0; rf < 4; ++rf)
#pragma unroll
        for (int cf = 0; cf < CF; ++cf)
          acc[rf][cf] = __builtin_amdgcn_mfma_f32_16x16x32_bf16(a[rf], B[cf][kf],
                                                                acc[rf][cf], 0, 0, 0);
    }
  }

  float bv[CF];
#pragma unroll
  for (int cf = 0; cf < CF; ++cf) bv[cf] = bias[colbase + cf * 16 + lr];

  float colS[CF], colQ[CF];
#pragma unroll
  for (int cf = 0; cf < CF; ++cf) { colS[cf] = 0.f; colQ[cf] = 0.f; }

  float* Cf = (float*)Cv;
  unsigned short* Cb = (unsigned short*)Cv;
#pragma unroll
  for (int rf = 0; rf < 4; ++rf) {
#pragma unroll
    for (int r = 0; r < 4; ++r) {
      int row = row0 + rf * 16 + lk * 4 + r;
      bool ok = row < M;
#pragma unroll
      for (int cf = 0; cf < CF; ++cf) {
        int col = colbase + cf * 16 + lr;
        float v = acc[rf][cf][r] + bv[cf];
        if (RELU) v = fmaxf(v, 0.f);
        if (ok) {
          if (OBF16)
            Cb[(size_t)row * NCOLS + col] = f2bf(v);
          else
            Cf[(size_t)row * NCOLS + col] = v;
          if (STATS) { colS[cf] += v; colQ[cf] += v * v; }
        }
      }
    }
  }

  if constexpr (STATS) {
#pragma unroll
    for (int cf = 0; cf < CF; ++cf) {
      float s = colS[cf], q = colQ[cf];
      s += __shfl_xor(s, 16); q += __shfl_xor(q, 16);
      s += __shfl_xor(s, 32); q += __shfl_xor(q, 32);
      if (lk == 0) {
        int col = colbase + cf * 16 + lr;
        atomicAdd(&stats[col], s);
        atomicAdd(&stats[D + col], q);
      }
    }
  }
}

// ---------------------------------------------------------------------------
__global__ __launch_bounds__(256) void k_bnprep(const float* __restrict__ stats,
                                                const float* __restrict__ gamma,
                                                const float* __restrict__ beta,
                                                float* __restrict__ bnp0,
                                                float* __restrict__ bnp1,
                                                float invM0, float invM1) {
  int i = threadIdx.x;
  if (i < 128) {
    float mu = stats[i] * invM0;
    float var = stats[D + i] * invM0 - mu * mu;
    float sc = rsqrtf(var + BN_EPS) * gamma[i];
    bnp0[i] = sc;
    bnp0[D + i] = beta[i] - mu * sc;
  } else {
    int d = i - 128;
    float mu = stats[2 * D + d] * invM1;
    float var = stats[3 * D + d] * invM1 - mu * mu;
    float sc = rsqrtf(var + BN_EPS) * gamma[d];
    bnp1[d] = sc;
    bnp1[D + d] = beta[d] - mu * sc;
  }
}

// final-layer BN (no relu), fp32 in place
__global__ __launch_bounds__(256) void k_bnfin(float* __restrict__ X, int M,
                                               const float* __restrict__ bnp) {
  int idx = blockIdx.x * 256 + threadIdx.x;
  int i = idx >> 5, c4 = idx & 31;
  if (i >= M) return;
  float4 v = *(float4*)(X + (size_t)i * D + c4 * 4);
  float4 sc = *(const float4*)(bnp + c4 * 4);
  float4 sh = *(const float4*)(bnp + D + c4 * 4);
  float4 o;
  o.x = fmaf(v.x, sc.x, sh.x); o.y = fmaf(v.y, sc.y, sh.y);
  o.z = fmaf(v.z, sc.z, sh.z); o.w = fmaf(v.w, sc.w, sh.w);
  *(float4*)(X + (size_t)i * D + c4 * 4) = o;
}

// ---------------------------------------------------------------------------
extern "C" void kernel_launch(void* const* d_in, const int* in_sizes, int n_in,
                              void* d_out, int out_size, void* d_ws,
                              size_t ws_size, hipStream_t stream) {
  const int* x0 = (const int*)d_in[0];
  const int* x1 = (const int*)d_in[1];
  const int* ei101 = (const int*)d_in[2];
  const int* ea101 = (const int*)d_in[3];
  const int* ei110 = (const int*)d_in[4];
  const int* ea110 = (const int*)d_in[5];
  const int* ei021 = (const int*)d_in[6];
  const int* ea021 = (const int*)d_in[7];
  const int* ei030 = (const int*)d_in[8];
  const int* ea030 = (const int*)d_in[9];
  const float* x_emb1 = (const float*)d_in[10];
  const float* x_emb2 = (const float*)d_in[11];
  const float* e_emb1 = (const float*)d_in[12];
  const float* e_emb2 = (const float*)d_in[13];
  const float* gin_w1 = (const float*)d_in[14];
  const float* gin_b1 = (const float*)d_in[15];
  const float* gin_w2 = (const float*)d_in[16];
  const float* gin_b2 = (const float*)d_in[17];
  const float* w110 = (const float*)d_in[18];
  const float* b110 = (const float*)d_in[19];
  const float* w021 = (const float*)d_in[20];
  const float* b021 = (const float*)d_in[21];
  const float* w030 = (const float*)d_in[22];
  const float* b030 = (const float*)d_in[23];
  const float* bn_gamma = (const float*)d_in[24];
  const float* bn_beta = (const float*)d_in[25];

  int n0 = in_sizes[0] / 2, n1 = in_sizes[1] / 2;
  int E = in_sizes[2] / 2;
  int nmax = n0 > n1 ? n0 : n1;

  float* h0f = (float*)d_out;
  float* h1f = h0f + (size_t)n0 * D;

  // ---- workspace layout ----
  char* p = (char*)d_ws;
  auto alloc = [&](size_t bytes) {
    char* r = p;
    p += (bytes + 63) & ~(size_t)63;
    return r;
  };
  unsigned short* h0r = (unsigned short*)alloc((size_t)n0 * D * 2);
  unsigned short* h1r = (unsigned short*)alloc((size_t)n1 * D * 2);
  unsigned short* z1b = (unsigned short*)alloc((size_t)n1 * D * 2);
  unsigned short* a021b = (unsigned short*)alloc((size_t)n1 * D * 2);
  unsigned short* a110b = (unsigned short*)alloc((size_t)n0 * D * 2);
  unsigned short* a030b = (unsigned short*)alloc((size_t)n0 * D * 2);
  unsigned short* hiddenb = (unsigned short*)alloc((size_t)n1 * 256 * 2);
  float* etbl = (float*)alloc(10 * D * 4);
  float* stats = (float*)alloc(4 * D * 4);
  float* bnp0 = (float*)alloc(2 * D * 4);
  float* bnp1 = (float*)alloc(2 * D * 4);
  unsigned short* wt110 = (unsigned short*)alloc(128 * 128 * 2);
  unsigned short* wt030 = (unsigned short*)alloc(128 * 128 * 2);
  unsigned short* wt021 = (unsigned short*)alloc(128 * 128 * 2);
  unsigned short* wtg1 = (unsigned short*)alloc(256 * 128 * 2);  // [N=256][K=128]
  unsigned short* wtg2 = (unsigned short*)alloc(128 * 256 * 2);  // [N=128][K=256]
  float* bias0 = (float*)alloc(128 * 4);
  float* biash = (float*)alloc(256 * 4);
  float* bias1 = (float*)alloc(128 * 4);

  EdgeArr EA;
  CsrPtrs cp;
  const int* eis[4] = {ei101, ei021, ei110, ei030};
  const int* eas[4] = {ea101, ea021, ea110, ea030};
  int ndst[4] = {n1, n1, n0, n0};
  for (int t = 0; t < 4; ++t) {
    cp.rp[t] = (int*)alloc((size_t)(nmax + 1) * 4);
    cp.cur[t] = (int*)alloc((size_t)nmax * 4);
    EA.pay[t] = (int*)alloc((size_t)E * 4);
    cp.n[t] = ndst[t];
    EA.ei[t] = eis[t];
    EA.ea[t] = eas[t];
    EA.cur[t] = cp.cur[t];
  }
  int* bsum = (int*)alloc(4 * MAXNB * 4);

  dim3 b256(256);

  // one-time: tables, embeddings, weight prep, CSR build (partitioned)
  k_etbl<<<5, b256, 0, stream>>>(e_emb1, e_emb2, etbl);
  k_embed<<<(n0 * 32 + 255) / 256, b256, 0, stream>>>(x0, x_emb1, x_emb2, h0r, n0);
  k_embed<<<(n1 * 32 + 255) / 256, b256, 0, stream>>>(x1, x_emb1, x_emb2, h1r, n1);
  k_wprep<<<64, b256, 0, stream>>>(w110, wt110, 128, 128, 0.05f);
  k_wprep<<<64, b256, 0, stream>>>(w030, wt030, 128, 128, 0.05f);
  k_wprep<<<64, b256, 0, stream>>>(w021, wt021, 128, 128, 0.05f);
  k_wprep<<<128, b256, 0, stream>>>(gin_w1, wtg1, 128, 256, 1.0f);
  k_wprep<<<128, b256, 0, stream>>>(gin_w2, wtg2, 256, 128, 0.5f);
  k_bprep<<<1, b256, 0, stream>>>(b110, b030, gin_b1, gin_b2, b021, bias0, biash, bias1);

  for (int t = 0; t < 4; ++t)
    hipMemsetAsync(cp.cur[t], 0, (size_t)ndst[t] * sizeof(int), stream);
  int rsz = (nmax + 7) / 8;
  int nchunks = (E + ECHUNK - 1) / ECHUNK;
  dim3 partGrid(nchunks * 8, 4);
  k_hist_part<<<partGrid, b256, 0, stream>>>(EA, E, rsz);
  hipMemsetAsync(bsum, 0, 4 * MAXNB * sizeof(int), stream);
  int nb = (nmax + 4095) / 4096;
  k_scan1<<<dim3(nb, 4), b256, 0, stream>>>(cp, bsum);
  k_scan2<<<1, dim3(64), 0, stream>>>(bsum);
  k_scan3<<<dim3(nb, 4), b256, 0, stream>>>(cp, bsum, E);
  k_fill_part<<<partGrid, b256, 0, stream>>>(EA, E, rsz);

  // merged gather args (types: z1, a021, a110, a030)
  GArgs GA;
  GA.src[0] = h1r; GA.ini[0] = h1r;     GA.bnp[0] = bnp1; GA.agg[0] = z1b;   GA.mode[0] = 2; GA.n[0] = n1;
  GA.src[1] = h0r; GA.ini[1] = nullptr; GA.bnp[1] = bnp0; GA.agg[1] = a021b; GA.mode[1] = 0; GA.n[1] = n1;
  GA.src[2] = h1r; GA.ini[2] = nullptr; GA.bnp[2] = bnp1; GA.agg[2] = a110b; GA.mode[2] = 0; GA.n[2] = n0;
  GA.src[3] = h0r; GA.ini[3] = h0r;     GA.bnp[3] = bnp0; GA.agg[3] = a030b; GA.mode[3] = 1; GA.n[3] = n0;
  for (int t = 0; t < 4; ++t) {
    GA.rp[t] = cp.rp[t];
    GA.pay[t] = EA.pay[t];
  }

  int mB0 = (n0 + 63) / 64, mB1 = (n1 + 63) / 64;
  dim3 gGrid((nmax + 15) / 16, 4);

  for (int layer = 0; layer < 3; ++layer) {
    GA.norm = (layer > 0) ? 1 : 0;
    k_gather_all<<<gGrid, b256, 0, stream>>>(GA, etbl);

    hipMemsetAsync(stats, 0, 4 * D * sizeof(float), stream);

    if (layer < 2) {
      // raw (pre-BN) bf16 outputs into h0r/h1r
      gemm_breg<128, 128, 128, false, true, true><<<mB0, b256, 0, stream>>>(
          a110b, wt110, a030b, wt030, bias0, h0r, n0, stats);
      gemm_breg<256, 128, 0, true, false, true><<<mB1, b256, 0, stream>>>(
          z1b, wtg1, nullptr, nullptr, biash, hiddenb, n1, nullptr);
      gemm_breg<128, 256, 128, false, true, true><<<mB1, b256, 0, stream>>>(
          hiddenb, wtg2, a021b, wt021, bias1, h1r, n1, stats + 2 * D);
    } else {
      // final layer: raw fp32 straight into d_out, BN applied in place after
      gemm_breg<128, 128, 128, false, true, false><<<mB0, b256, 0, stream>>>(
          a110b, wt110, a030b, wt030, bias0, h0f, n0, stats);
      gemm_breg<256, 128, 0, true, false, true><<<mB1, b256, 0, stream>>>(
          z1b, wtg1, nullptr, nullptr, biash, hiddenb, n1, nullptr);
      gemm_breg<128, 256, 128, false, true, false><<<mB1, b256, 0, stream>>>(
          hiddenb, wtg2, a021b, wt021, bias1, h1f, n1, stats + 2 * D);
    }

    k_bnprep<<<1, b256, 0, stream>>>(stats, bn_gamma + layer * D,
                                     bn_beta + layer * D, bnp0, bnp1,
                                     1.0f / n0, 1.0f / n1);
    if (layer == 2) {
      k_bnfin<<<(n0 * 32 + 255) / 256, b256, 0, stream>>>(h0f, n0, bnp0);
      k_bnfin<<<(n1 * 32 + 255) / 256, b256, 0, stream>>>(h1f, n1, bnp1);
    }
  }
}